// Round 2
// baseline (1412.220 us; speedup 1.0000x reference)
//
#include <hip/hip_runtime.h>
#include <hip/hip_bf16.h>

typedef __hip_bfloat16 bf16;

#define NB 32
#define NH 64
#define NW 64
#define NC 256
#define NHID 128
#define NQKV 384
#define NROWS (NB * NH * NW)  // 131072
#define SMSCALE 0.17677669529663687f  // 32^-0.5

// ---------------- K1: qkv = x @ w_qkv  (fp32 in, fp32 accum, fp32 out) ----------------
__global__ __launch_bounds__(256) void k_gemm_qkv(const float* __restrict__ x,
                                                  const float* __restrict__ w,
                                                  float* __restrict__ qkv) {
  __shared__ float As[64][17];
  __shared__ float Bs[16][68];
  const int tx = threadIdx.x, ty = threadIdx.y;
  const int t = ty * 16 + tx;
  const int rowBase = blockIdx.y * 64;
  const int colBase = blockIdx.x * 64;
  float acc[4][4] = {};
  for (int k0 = 0; k0 < NC; k0 += 16) {
#pragma unroll
    for (int i = 0; i < 4; ++i) {
      int e = t + 256 * i;
      int r = e >> 4, kk = e & 15;
      As[r][kk] = x[(size_t)(rowBase + r) * NC + k0 + kk];
    }
#pragma unroll
    for (int i = 0; i < 4; ++i) {
      int e = t + 256 * i;
      int kk = e >> 6, c = e & 63;
      Bs[kk][c] = w[(size_t)(k0 + kk) * NQKV + colBase + c];
    }
    __syncthreads();
#pragma unroll
    for (int kk = 0; kk < 16; ++kk) {
      float a[4], b[4];
#pragma unroll
      for (int i = 0; i < 4; ++i) a[i] = As[ty * 4 + i][kk];
#pragma unroll
      for (int j = 0; j < 4; ++j) b[j] = Bs[kk][tx * 4 + j];
#pragma unroll
      for (int i = 0; i < 4; ++i)
#pragma unroll
        for (int j = 0; j < 4; ++j) acc[i][j] += a[i] * b[j];
    }
    __syncthreads();
  }
#pragma unroll
  for (int i = 0; i < 4; ++i)
#pragma unroll
    for (int j = 0; j < 4; ++j)
      qkv[(size_t)(rowBase + ty * 4 + i) * NQKV + colBase + tx * 4 + j] = acc[i][j];
}

// ---------------- K2a: q = softmax over W axis, * scale (in place) ----------------
// one block per (b, h); thread = channel c in [0,128)
__global__ __launch_bounds__(128) void k_softmax_q(float* __restrict__ qkv) {
  const int bd = blockIdx.x;  // b*64 + d
  const int c = threadIdx.x;
  size_t base = (size_t)bd * 64 * NQKV + c;
  float v[64];
  float m = -1e30f;
#pragma unroll
  for (int n = 0; n < 64; ++n) {
    v[n] = qkv[base + (size_t)n * NQKV];
    m = fmaxf(m, v[n]);
  }
  float s = 0.f;
#pragma unroll
  for (int n = 0; n < 64; ++n) {
    v[n] = __expf(v[n] - m);
    s += v[n];
  }
  float r = SMSCALE / s;
#pragma unroll
  for (int n = 0; n < 64; ++n) qkv[base + (size_t)n * NQKV] = v[n] * r;
}

// ---------------- K2b: k = softmax over channel axis (in place) ----------------
// one wave per spatial row; 4 waves per block
__global__ __launch_bounds__(256) void k_softmax_k(float* __restrict__ qkv) {
  const int lane = threadIdx.x & 63;
  const int wid = threadIdx.x >> 6;
  const int row = blockIdx.x * 4 + wid;  // < 131072
  size_t base = (size_t)row * NQKV + NHID + lane;
  float v0 = qkv[base];
  float v1 = qkv[base + 64];
  float m = fmaxf(v0, v1);
#pragma unroll
  for (int off = 32; off; off >>= 1) m = fmaxf(m, __shfl_xor(m, off, 64));
  v0 = __expf(v0 - m);
  v1 = __expf(v1 - m);
  float s = v0 + v1;
#pragma unroll
  for (int off = 32; off; off >>= 1) s += __shfl_xor(s, off, 64);
  float r = 1.f / s;
  qkv[base] = v0 * r;
  qkv[base + 64] = v1 * r;
}

// ---------------- K3: per (b,ch): ctx = K V^T ; out = ctx^T Q ----------------
// ctx[d][e] = sum_n K[d][n] V[e][n];  out[e][n] = sum_d ctx[d][e] Q[d][n]
__global__ __launch_bounds__(256) void k_attn(const float* __restrict__ qkv,
                                              bf16* __restrict__ outb) {
  const int ch = blockIdx.x;  // 0..127
  const int b = blockIdx.y;   // 0..31
  __shared__ float S1[64 * 65];  // K, then ctx
  __shared__ float S2[64 * 65];  // V, then Q
  const int tx = threadIdx.x, ty = threadIdx.y;
  const int t = ty * 16 + tx;
  const size_t qbase = (size_t)b * 64 * 64 * NQKV;
#pragma unroll
  for (int i = 0; i < 16; ++i) {
    int e = t + 256 * i;  // 0..4095
    int d = e >> 6, n = e & 63;
    size_t a = qbase + (size_t)(d * 64 + n) * NQKV;
    S1[d * 65 + n] = qkv[a + NHID + ch];      // k (softmaxed)
    S2[d * 65 + n] = qkv[a + 2 * NHID + ch];  // v
  }
  __syncthreads();
  float ctx[4][4] = {};
  for (int n = 0; n < 64; ++n) {
    float kv[4], vv[4];
#pragma unroll
    for (int i = 0; i < 4; ++i) kv[i] = S1[(ty * 4 + i) * 65 + n];
#pragma unroll
    for (int j = 0; j < 4; ++j) vv[j] = S2[(tx * 4 + j) * 65 + n];
#pragma unroll
    for (int i = 0; i < 4; ++i)
#pragma unroll
      for (int j = 0; j < 4; ++j) ctx[i][j] += kv[i] * vv[j];
  }
  __syncthreads();
  // stash ctx (d = ty*4+i, e = tx*4+j) into S1; reload Q into S2
#pragma unroll
  for (int i = 0; i < 4; ++i)
#pragma unroll
    for (int j = 0; j < 4; ++j) S1[(ty * 4 + i) * 65 + tx * 4 + j] = ctx[i][j];
#pragma unroll
  for (int i = 0; i < 16; ++i) {
    int e = t + 256 * i;
    int d = e >> 6, n = e & 63;
    S2[d * 65 + n] = qkv[qbase + (size_t)(d * 64 + n) * NQKV + ch];  // q (softmaxed*scale)
  }
  __syncthreads();
  float o[4][4] = {};
  for (int d = 0; d < 64; ++d) {
    float cv[4], qv[4];
#pragma unroll
    for (int i = 0; i < 4; ++i) cv[i] = S1[d * 65 + ty * 4 + i];
#pragma unroll
    for (int j = 0; j < 4; ++j) qv[j] = S2[d * 65 + tx * 4 + j];
#pragma unroll
    for (int i = 0; i < 4; ++i)
#pragma unroll
      for (int j = 0; j < 4; ++j) o[i][j] += cv[i] * qv[j];
  }
  // out layout [b, e, n, ch]
#pragma unroll
  for (int i = 0; i < 4; ++i)
#pragma unroll
    for (int j = 0; j < 4; ++j) {
      size_t idx = ((size_t)(b * 64 + ty * 4 + i) * 64 + tx * 4 + j) * NHID + ch;
      outb[idx] = __float2bfloat16(o[i][j]);
    }
}

// ---------------- K4: y = attn @ w_out + b_out -> fp32 d_out, + per-batch sums ----------------
__global__ __launch_bounds__(256) void k_gemm_out(const bf16* __restrict__ a,
                                                  const float* __restrict__ w,
                                                  const float* __restrict__ bias,
                                                  float* __restrict__ y,
                                                  float* __restrict__ sums) {
  __shared__ float As[64][17];
  __shared__ float Bs[16][68];
  __shared__ float red[8];
  const int tx = threadIdx.x, ty = threadIdx.y;
  const int t = ty * 16 + tx;
  const int rowBase = blockIdx.y * 64;
  const int colBase = blockIdx.x * 64;
  float acc[4][4] = {};
  for (int k0 = 0; k0 < NHID; k0 += 16) {
#pragma unroll
    for (int i = 0; i < 4; ++i) {
      int e = t + 256 * i;
      int r = e >> 4, kk = e & 15;
      As[r][kk] = __bfloat162float(a[(size_t)(rowBase + r) * NHID + k0 + kk]);
    }
#pragma unroll
    for (int i = 0; i < 4; ++i) {
      int e = t + 256 * i;
      int kk = e >> 6, c = e & 63;
      Bs[kk][c] = w[(size_t)(k0 + kk) * NC + colBase + c];
    }
    __syncthreads();
#pragma unroll
    for (int kk = 0; kk < 16; ++kk) {
      float av[4], bv[4];
#pragma unroll
      for (int i = 0; i < 4; ++i) av[i] = As[ty * 4 + i][kk];
#pragma unroll
      for (int j = 0; j < 4; ++j) bv[j] = Bs[kk][tx * 4 + j];
#pragma unroll
      for (int i = 0; i < 4; ++i)
#pragma unroll
        for (int j = 0; j < 4; ++j) acc[i][j] += av[i] * bv[j];
    }
    __syncthreads();
  }
  float bsv[4];
#pragma unroll
  for (int j = 0; j < 4; ++j) bsv[j] = bias[colBase + tx * 4 + j];
  float ls = 0.f, lss = 0.f;
#pragma unroll
  for (int i = 0; i < 4; ++i)
#pragma unroll
    for (int j = 0; j < 4; ++j) {
      float v = acc[i][j] + bsv[j];
      y[(size_t)(rowBase + ty * 4 + i) * NC + colBase + tx * 4 + j] = v;
      ls += v;
      lss += v * v;
    }
#pragma unroll
  for (int off = 32; off; off >>= 1) {
    ls += __shfl_xor(ls, off, 64);
    lss += __shfl_xor(lss, off, 64);
  }
  const int wid = t >> 6, lane = t & 63;
  if (lane == 0) {
    red[wid] = ls;
    red[4 + wid] = lss;
  }
  __syncthreads();
  if (t == 0) {
    float S = red[0] + red[1] + red[2] + red[3];
    float SS = red[4] + red[5] + red[6] + red[7];
    int b = rowBase >> 12;  // 4096 rows per batch
    atomicAdd(&sums[2 * b], S);
    atomicAdd(&sums[2 * b + 1], SS);
  }
}

// ---------------- K5: GroupNorm(1 group) finalize, in place on fp32 d_out ----------------
__global__ __launch_bounds__(256) void k_gnorm(float* __restrict__ y,
                                               const float* __restrict__ sums,
                                               const float* __restrict__ gs,
                                               const float* __restrict__ gb) {
  size_t i0 = ((size_t)blockIdx.x * 256 + threadIdx.x) * 4;
  int b = (int)(i0 >> 20);  // 64*64*256 = 1048576 elems per batch
  int c = (int)(i0 & 255);
  const float invN = 1.0f / 1048576.0f;
  float mean = sums[2 * b] * invN;
  float var = sums[2 * b + 1] * invN - mean * mean;
  float inv = rsqrtf(var + 1e-6f);
  float4 v = *((const float4*)(y + i0));
  float4 g = *((const float4*)(gs + c));
  float4 bb = *((const float4*)(gb + c));
  float4 r;
  r.x = (v.x - mean) * inv * g.x + bb.x;
  r.y = (v.y - mean) * inv * g.y + bb.y;
  r.z = (v.z - mean) * inv * g.z + bb.z;
  r.w = (v.w - mean) * inv * g.w + bb.w;
  *((float4*)(y + i0)) = r;
}

extern "C" void kernel_launch(void* const* d_in, const int* in_sizes, int n_in,
                              void* d_out, int out_size, void* d_ws, size_t ws_size,
                              hipStream_t stream) {
  const float* x = (const float*)d_in[0];
  const float* w_qkv = (const float*)d_in[1];
  const float* w_out = (const float*)d_in[2];
  const float* b_out = (const float*)d_in[3];
  const float* gn_scale = (const float*)d_in[4];
  const float* gn_bias = (const float*)d_in[5];
  float* out = (float*)d_out;

  char* ws = (char*)d_ws;
  float* qkv = (float*)ws;                                    // 131072*384*4 = 192 MiB
  bf16* attnbuf = (bf16*)(ws + (size_t)201326592);            // 131072*128*2 = 32 MiB
  float* sums = (float*)(ws + (size_t)201326592 + 33554432);  // 64 floats

  hipMemsetAsync(sums, 0, 64 * sizeof(float), stream);

  k_gemm_qkv<<<dim3(6, 2048), dim3(16, 16), 0, stream>>>(x, w_qkv, qkv);
  k_softmax_q<<<2048, 128, 0, stream>>>(qkv);
  k_softmax_k<<<NROWS / 4, 256, 0, stream>>>(qkv);
  k_attn<<<dim3(128, 32), dim3(16, 16), 0, stream>>>(qkv, attnbuf);
  k_gemm_out<<<dim3(4, 2048), dim3(16, 16), 0, stream>>>(attnbuf, w_out, b_out, out, sums);
  k_gnorm<<<32768, 256, 0, stream>>>(out, sums, gn_scale, gn_bias);
}

// Round 3
// 932.863 us; speedup vs baseline: 1.5139x; 1.5139x over previous
//
#include <hip/hip_runtime.h>
#include <hip/hip_bf16.h>

typedef __hip_bfloat16 bf16;

#define NB 32
#define NC 256
#define NHID 128
#define NQKV 384
#define NROWS (NB * 64 * 64)          // 131072
#define SMSCALE 0.17677669529663687f  // 32^-0.5

// ---------------- K1: qkv = x @ w_qkv, written transposed to qt/kt/vt [b][ch][d*64+n] ----------------
__global__ __launch_bounds__(256) void k_gemm_qkv(const float* __restrict__ x,
                                                  const float* __restrict__ w,
                                                  float* __restrict__ qt,
                                                  float* __restrict__ kt,
                                                  float* __restrict__ vt) {
  __shared__ float As[64][17];
  __shared__ float Bs[16][68];
  const int tx = threadIdx.x, ty = threadIdx.y;
  const int t = ty * 16 + tx;
  const int rowBase = blockIdx.y * 64;  // fixed (b, d), n spans 0..63
  const int colBase = blockIdx.x * 64;
  const int b = rowBase >> 12;
  const int d = (rowBase >> 6) & 63;
  float acc[4][4] = {};
  for (int k0 = 0; k0 < NC; k0 += 16) {
#pragma unroll
    for (int i = 0; i < 4; ++i) {
      int e = t + 256 * i;
      int r = e >> 4, kk = e & 15;
      As[r][kk] = x[(size_t)(rowBase + r) * NC + k0 + kk];
    }
#pragma unroll
    for (int i = 0; i < 4; ++i) {
      int e = t + 256 * i;
      int kk = e >> 6, c = e & 63;
      Bs[kk][c] = w[(size_t)(k0 + kk) * NQKV + colBase + c];
    }
    __syncthreads();
#pragma unroll
    for (int kk = 0; kk < 16; ++kk) {
      float a[4], bv[4];
#pragma unroll
      for (int i = 0; i < 4; ++i) a[i] = As[ty * 4 + i][kk];
#pragma unroll
      for (int j = 0; j < 4; ++j) bv[j] = Bs[kk][tx * 4 + j];
#pragma unroll
      for (int i = 0; i < 4; ++i)
#pragma unroll
        for (int j = 0; j < 4; ++j) acc[i][j] += a[i] * bv[j];
    }
    __syncthreads();
  }
  // transposed epilogue: acc rows i index n, cols j index channel
  float* outp = (colBase < 128) ? qt : (colBase < 256 ? kt : vt);
  const int chBase = colBase & 127;
#pragma unroll
  for (int j = 0; j < 4; ++j) {
    int ch = chBase + tx * 4 + j;
    size_t a = (((size_t)(b * 128 + ch)) << 12) + (d << 6) + ty * 4;
    float4 v;
    v.x = acc[0][j]; v.y = acc[1][j]; v.z = acc[2][j]; v.w = acc[3][j];
    *(float4*)(outp + a) = v;
  }
}

// ---------------- K2: k-softmax over channel axis, on kt layout ----------------
// block = (b, d); thread: n = t&63, quarter q = t>>6 handles 32 channels
__global__ __launch_bounds__(256) void k_softmax_k(float* __restrict__ kt) {
  const int b = blockIdx.x >> 6, d = blockIdx.x & 63;
  const int t = threadIdx.x;
  const int n = t & 63, q = t >> 6;
  __shared__ float red[4][64];
  const size_t base = (((size_t)(b * 128)) << 12) + (d << 6) + n;
  float v[32];
  float m = -1e30f;
#pragma unroll
  for (int c = 0; c < 32; ++c) {
    v[c] = kt[base + (((size_t)(q * 32 + c)) << 12)];
    m = fmaxf(m, v[c]);
  }
  red[q][n] = m;
  __syncthreads();
  m = fmaxf(fmaxf(red[0][n], red[1][n]), fmaxf(red[2][n], red[3][n]));
  float s = 0.f;
#pragma unroll
  for (int c = 0; c < 32; ++c) {
    v[c] = __expf(v[c] - m);
    s += v[c];
  }
  __syncthreads();
  red[q][n] = s;
  __syncthreads();
  s = red[0][n] + red[1][n] + red[2][n] + red[3][n];
  float r = 1.f / s;
#pragma unroll
  for (int c = 0; c < 32; ++c)
    kt[base + (((size_t)(q * 32 + c)) << 12)] = v[c] * r;
}

// ---------------- K3: per (b,ch): ctx = K V^T ; out = ctx^T softmax(Q)*scale ----------------
__global__ __launch_bounds__(256) void k_attn(const float* __restrict__ kt,
                                              const float* __restrict__ vt,
                                              const float* __restrict__ qt,
                                              float* __restrict__ at) {
  const int ch = blockIdx.x;
  const int b = blockIdx.y;
  __shared__ float S1[64 * 65];  // K, then ctx
  __shared__ float S2[64 * 65];  // V, then Q
  const int tx = threadIdx.x, ty = threadIdx.y;
  const int t = ty * 16 + tx;
  const size_t base = ((size_t)(b * 128 + ch)) << 12;
  // load K, V (coalesced float4)
#pragma unroll
  for (int i = 0; i < 4; ++i) {
    int e = i * 1024 + t * 4;
    int d = e >> 6, n = e & 63;
    float4 kv = *(const float4*)(kt + base + e);
    float4 vv = *(const float4*)(vt + base + e);
    S1[d * 65 + n] = kv.x; S1[d * 65 + n + 1] = kv.y; S1[d * 65 + n + 2] = kv.z; S1[d * 65 + n + 3] = kv.w;
    S2[d * 65 + n] = vv.x; S2[d * 65 + n + 1] = vv.y; S2[d * 65 + n + 2] = vv.z; S2[d * 65 + n + 3] = vv.w;
  }
  __syncthreads();
  float ctx[4][4] = {};
  for (int n = 0; n < 64; ++n) {
    float kv[4], vv[4];
#pragma unroll
    for (int i = 0; i < 4; ++i) kv[i] = S1[(ty * 4 + i) * 65 + n];
#pragma unroll
    for (int j = 0; j < 4; ++j) vv[j] = S2[(tx * 4 + j) * 65 + n];
#pragma unroll
    for (int i = 0; i < 4; ++i)
#pragma unroll
      for (int j = 0; j < 4; ++j) ctx[i][j] += kv[i] * vv[j];
  }
  __syncthreads();
  // stash ctx into S1; load Q into S2
#pragma unroll
  for (int i = 0; i < 4; ++i)
#pragma unroll
    for (int j = 0; j < 4; ++j) S1[(ty * 4 + i) * 65 + tx * 4 + j] = ctx[i][j];
#pragma unroll
  for (int i = 0; i < 4; ++i) {
    int e = i * 1024 + t * 4;
    int d = e >> 6, n = e & 63;
    float4 qv = *(const float4*)(qt + base + e);
    S2[d * 65 + n] = qv.x; S2[d * 65 + n + 1] = qv.y; S2[d * 65 + n + 2] = qv.z; S2[d * 65 + n + 3] = qv.w;
  }
  __syncthreads();
  // fused softmax over n per row d of Q, * SMSCALE
  {
    const int d = t >> 2, qq = t & 3;
    float vals[16];
    float m = -1e30f;
#pragma unroll
    for (int k = 0; k < 16; ++k) {
      vals[k] = S2[d * 65 + qq * 16 + k];
      m = fmaxf(m, vals[k]);
    }
    m = fmaxf(m, __shfl_xor(m, 1, 64));
    m = fmaxf(m, __shfl_xor(m, 2, 64));
    float s = 0.f;
#pragma unroll
    for (int k = 0; k < 16; ++k) {
      vals[k] = __expf(vals[k] - m);
      s += vals[k];
    }
    s += __shfl_xor(s, 1, 64);
    s += __shfl_xor(s, 2, 64);
    float r = SMSCALE / s;
#pragma unroll
    for (int k = 0; k < 16; ++k) S2[d * 65 + qq * 16 + k] = vals[k] * r;
  }
  __syncthreads();
  float o[4][4] = {};
  for (int d = 0; d < 64; ++d) {
    float cv[4], qv[4];
#pragma unroll
    for (int i = 0; i < 4; ++i) cv[i] = S1[d * 65 + ty * 4 + i];
#pragma unroll
    for (int j = 0; j < 4; ++j) qv[j] = S2[d * 65 + tx * 4 + j];
#pragma unroll
    for (int i = 0; i < 4; ++i)
#pragma unroll
      for (int j = 0; j < 4; ++j) o[i][j] += cv[i] * qv[j];
  }
  // write at[b][ch][e*64+n], e = ty*4+i, n = tx*4+j (coalesced float4)
#pragma unroll
  for (int i = 0; i < 4; ++i) {
    float4 v;
    v.x = o[i][0]; v.y = o[i][1]; v.z = o[i][2]; v.w = o[i][3];
    *(float4*)(at + base + (ty * 4 + i) * 64 + tx * 4) = v;
  }
}

// ---------------- K4: y = attn @ w_out + b_out (A stored K-major) + per-batch sums ----------------
__global__ __launch_bounds__(256) void k_gemm_out(const float* __restrict__ at,
                                                  const float* __restrict__ w,
                                                  const float* __restrict__ bias,
                                                  float* __restrict__ y,
                                                  float* __restrict__ sums) {
  __shared__ float As[64][17];
  __shared__ float Bs[16][68];
  __shared__ float red[8];
  const int tx = threadIdx.x, ty = threadIdx.y;
  const int t = ty * 16 + tx;
  const int rowBase = blockIdx.y * 64;
  const int colBase = blockIdx.x * 64;
  const int b = rowBase >> 12;
  const int r0 = rowBase & 4095;
  const size_t abase = (((size_t)(b * 128)) << 12) + r0;
  float acc[4][4] = {};
  for (int k0 = 0; k0 < NHID; k0 += 16) {
    {
      int r = t & 63, kq = t >> 6;
#pragma unroll
      for (int i = 0; i < 4; ++i) {
        int kk = kq * 4 + i;
        As[r][kk] = at[abase + (((size_t)(k0 + kk)) << 12) + r];
      }
    }
#pragma unroll
    for (int i = 0; i < 4; ++i) {
      int e = t + 256 * i;
      int kk = e >> 6, c = e & 63;
      Bs[kk][c] = w[(size_t)(k0 + kk) * NC + colBase + c];
    }
    __syncthreads();
#pragma unroll
    for (int kk = 0; kk < 16; ++kk) {
      float av[4], bv[4];
#pragma unroll
      for (int i = 0; i < 4; ++i) av[i] = As[ty * 4 + i][kk];
#pragma unroll
      for (int j = 0; j < 4; ++j) bv[j] = Bs[kk][tx * 4 + j];
#pragma unroll
      for (int i = 0; i < 4; ++i)
#pragma unroll
        for (int j = 0; j < 4; ++j) acc[i][j] += av[i] * bv[j];
    }
    __syncthreads();
  }
  float bsv[4];
#pragma unroll
  for (int j = 0; j < 4; ++j) bsv[j] = bias[colBase + tx * 4 + j];
  float ls = 0.f, lss = 0.f;
#pragma unroll
  for (int i = 0; i < 4; ++i)
#pragma unroll
    for (int j = 0; j < 4; ++j) {
      float v = acc[i][j] + bsv[j];
      y[(size_t)(rowBase + ty * 4 + i) * NC + colBase + tx * 4 + j] = v;
      ls += v;
      lss += v * v;
    }
#pragma unroll
  for (int off = 32; off; off >>= 1) {
    ls += __shfl_xor(ls, off, 64);
    lss += __shfl_xor(lss, off, 64);
  }
  const int wid = t >> 6, lane = t & 63;
  if (lane == 0) {
    red[wid] = ls;
    red[4 + wid] = lss;
  }
  __syncthreads();
  if (t == 0) {
    float S = red[0] + red[1] + red[2] + red[3];
    float SS = red[4] + red[5] + red[6] + red[7];
    atomicAdd(&sums[2 * b], S);
    atomicAdd(&sums[2 * b + 1], SS);
  }
}

// ---------------- K5: GroupNorm(1 group) finalize, in place on fp32 d_out ----------------
__global__ __launch_bounds__(256) void k_gnorm(float* __restrict__ y,
                                               const float* __restrict__ sums,
                                               const float* __restrict__ gs,
                                               const float* __restrict__ gb) {
  size_t i0 = ((size_t)blockIdx.x * 256 + threadIdx.x) * 4;
  int b = (int)(i0 >> 20);  // 64*64*256 = 1048576 elems per batch
  int c = (int)(i0 & 255);
  const float invN = 1.0f / 1048576.0f;
  float mean = sums[2 * b] * invN;
  float var = sums[2 * b + 1] * invN - mean * mean;
  float inv = rsqrtf(var + 1e-6f);
  float4 v = *((const float4*)(y + i0));
  float4 g = *((const float4*)(gs + c));
  float4 bb = *((const float4*)(gb + c));
  float4 r;
  r.x = (v.x - mean) * inv * g.x + bb.x;
  r.y = (v.y - mean) * inv * g.y + bb.y;
  r.z = (v.z - mean) * inv * g.z + bb.z;
  r.w = (v.w - mean) * inv * g.w + bb.w;
  *((float4*)(y + i0)) = r;
}

extern "C" void kernel_launch(void* const* d_in, const int* in_sizes, int n_in,
                              void* d_out, int out_size, void* d_ws, size_t ws_size,
                              hipStream_t stream) {
  const float* x = (const float*)d_in[0];
  const float* w_qkv = (const float*)d_in[1];
  const float* w_out = (const float*)d_in[2];
  const float* b_out = (const float*)d_in[3];
  const float* gn_scale = (const float*)d_in[4];
  const float* gn_bias = (const float*)d_in[5];
  float* out = (float*)d_out;

  char* ws = (char*)d_ws;
  const size_t SLAB = (size_t)67108864;  // 64 MiB
  float* qt = (float*)ws;
  float* kt = (float*)(ws + SLAB);
  float* vt = (float*)(ws + 2 * SLAB);
  float* at = qt;  // alias: each k_attn block consumes its qt slice before writing at slice
  float* sums = (float*)(ws + 3 * SLAB);

  hipMemsetAsync(sums, 0, 64 * sizeof(float), stream);

  k_gemm_qkv<<<dim3(6, 2048), dim3(16, 16), 0, stream>>>(x, w_qkv, qt, kt, vt);
  k_softmax_k<<<2048, 256, 0, stream>>>(kt);
  k_attn<<<dim3(128, 32), dim3(16, 16), 0, stream>>>(kt, vt, qt, at);
  k_gemm_out<<<dim3(4, 2048), dim3(16, 16), 0, stream>>>(at, w_out, b_out, out, sums);
  k_gnorm<<<32768, 256, 0, stream>>>(out, sums, gn_scale, gn_bias);
}

// Round 4
// 539.637 us; speedup vs baseline: 2.6170x; 1.7287x over previous
//
#include <hip/hip_runtime.h>
#include <hip/hip_bf16.h>

typedef __hip_bfloat16 bf16;
typedef float f32x4 __attribute__((ext_vector_type(4)));
typedef short bf16x8 __attribute__((ext_vector_type(8)));
typedef short s16x4 __attribute__((ext_vector_type(4)));

#define NB 32
#define NC 256
#define NHID 128
#define NQKV 384
#define SMSCALE 0.17677669529663687f  // 32^-0.5

// fp32 -> bf16 round-to-nearest-even (finite inputs)
__device__ __forceinline__ short f2bf(float f) {
  union { float f; unsigned u; } v;
  v.f = f;
  return (short)((v.u + 0x7fffu + ((v.u >> 16) & 1u)) >> 16);
}

// ---------------- K0: weight prep: bf16 + transpose to K-contiguous ----------------
// wqt[n=384][k=256] <- w_qkv[k][n];  wot[c=256][k=128] <- w_out[k][c]
__global__ __launch_bounds__(256) void k_prep_w(const float* __restrict__ wqkv,
                                                const float* __restrict__ wout,
                                                short* __restrict__ wqt,
                                                short* __restrict__ wot) {
  int i = blockIdx.x * 256 + threadIdx.x;
  if (i < 98304) {
    int n = i >> 8, k = i & 255;
    wqt[i] = f2bf(wqkv[(size_t)k * NQKV + n]);
  }
  if (i < 32768) {
    int c = i >> 7, k = i & 127;
    wot[i] = f2bf(wout[(size_t)k * NC + c]);
  }
}

// ---------------- K1: qkv = x @ w_qkv via MFMA, LDS-free, transposed epilogue ----------------
// block: 64 rows (one (b,d) slice), full N=384; 4 waves, wave w owns N-strip [w*96, w*96+96)
__global__ __launch_bounds__(256) void k_gemm_qkv(const float* __restrict__ x,
                                                  const short* __restrict__ wqt,
                                                  float* __restrict__ qt,
                                                  float* __restrict__ kt,
                                                  float* __restrict__ vt) {
  const int t = threadIdx.x;
  const int lane = t & 63;
  const int w = t >> 6;
  const int l15 = lane & 15;
  const int q = lane >> 4;
  const int rowBase = blockIdx.x * 64;
  const int b = rowBase >> 12;
  const int d = (rowBase >> 6) & 63;

  f32x4 acc[4][6] = {};

  for (int ks = 0; ks < 8; ++ks) {
    const int k0 = ks * 32 + q * 8;
    bf16x8 afr[4];
#pragma unroll
    for (int mi = 0; mi < 4; ++mi) {
      const float* ap = x + (size_t)(rowBase + mi * 16 + l15) * NC + k0;
      float4 lo = *(const float4*)ap;
      float4 hi = *(const float4*)(ap + 4);
      bf16x8 a;
      a[0] = f2bf(lo.x); a[1] = f2bf(lo.y); a[2] = f2bf(lo.z); a[3] = f2bf(lo.w);
      a[4] = f2bf(hi.x); a[5] = f2bf(hi.y); a[6] = f2bf(hi.z); a[7] = f2bf(hi.w);
      afr[mi] = a;
    }
#pragma unroll
    for (int nj = 0; nj < 6; ++nj) {
      const int n = w * 96 + nj * 16 + l15;
      bf16x8 bfr = *(const bf16x8*)(wqt + (size_t)n * 256 + k0);
#pragma unroll
      for (int mi = 0; mi < 4; ++mi)
        acc[mi][nj] = __builtin_amdgcn_mfma_f32_16x16x32_bf16(afr[mi], bfr, acc[mi][nj], 0, 0, 0);
    }
  }
  // epilogue: C-frag col(l15) = channel, row(q*4+rg) = spatial n; write transposed slabs
#pragma unroll
  for (int mi = 0; mi < 4; ++mi)
#pragma unroll
    for (int nj = 0; nj < 6; ++nj) {
      int n_sp = mi * 16 + q * 4;
      int chg = w * 96 + nj * 16 + l15;
      float* outp = (chg < 128) ? qt : (chg < 256 ? kt : vt);
      int ch = chg & 127;
      float4 v;
      v.x = acc[mi][nj][0]; v.y = acc[mi][nj][1]; v.z = acc[mi][nj][2]; v.w = acc[mi][nj][3];
      *(float4*)(outp + (((size_t)(b * 128 + ch)) << 12) + (d << 6) + n_sp) = v;
    }
}

// ---------------- K2: k-softmax over channel axis, on kt layout ----------------
__global__ __launch_bounds__(256) void k_softmax_k(float* __restrict__ kt) {
  const int b = blockIdx.x >> 6, d = blockIdx.x & 63;
  const int t = threadIdx.x;
  const int n = t & 63, q = t >> 6;
  __shared__ float red[4][64];
  const size_t base = (((size_t)(b * 128)) << 12) + (d << 6) + n;
  float v[32];
  float m = -1e30f;
#pragma unroll
  for (int c = 0; c < 32; ++c) {
    v[c] = kt[base + (((size_t)(q * 32 + c)) << 12)];
    m = fmaxf(m, v[c]);
  }
  red[q][n] = m;
  __syncthreads();
  m = fmaxf(fmaxf(red[0][n], red[1][n]), fmaxf(red[2][n], red[3][n]));
  float s = 0.f;
#pragma unroll
  for (int c = 0; c < 32; ++c) {
    v[c] = __expf(v[c] - m);
    s += v[c];
  }
  __syncthreads();
  red[q][n] = s;
  __syncthreads();
  s = red[0][n] + red[1][n] + red[2][n] + red[3][n];
  float r = 1.f / s;
#pragma unroll
  for (int c = 0; c < 32; ++c)
    kt[base + (((size_t)(q * 32 + c)) << 12)] = v[c] * r;
}

// ---------------- K3: per (b,ch): ctx = K V^T ; out = ctx^T softmax(Q)*scale ----------------
__global__ __launch_bounds__(256) void k_attn(const float* __restrict__ kt,
                                              const float* __restrict__ vt,
                                              const float* __restrict__ qt,
                                              float* __restrict__ at) {
  const int ch = blockIdx.x;
  const int b = blockIdx.y;
  __shared__ float S1[64 * 65];  // K, then ctx
  __shared__ float S2[64 * 65];  // V, then Q
  const int tx = threadIdx.x & 15, ty = threadIdx.x >> 4;
  const int t = threadIdx.x;
  const size_t base = ((size_t)(b * 128 + ch)) << 12;
#pragma unroll
  for (int i = 0; i < 4; ++i) {
    int e = i * 1024 + t * 4;
    int d = e >> 6, n = e & 63;
    float4 kv = *(const float4*)(kt + base + e);
    float4 vv = *(const float4*)(vt + base + e);
    S1[d * 65 + n] = kv.x; S1[d * 65 + n + 1] = kv.y; S1[d * 65 + n + 2] = kv.z; S1[d * 65 + n + 3] = kv.w;
    S2[d * 65 + n] = vv.x; S2[d * 65 + n + 1] = vv.y; S2[d * 65 + n + 2] = vv.z; S2[d * 65 + n + 3] = vv.w;
  }
  __syncthreads();
  float ctx[4][4] = {};
  for (int n = 0; n < 64; ++n) {
    float kv[4], vv[4];
#pragma unroll
    for (int i = 0; i < 4; ++i) kv[i] = S1[(ty * 4 + i) * 65 + n];
#pragma unroll
    for (int j = 0; j < 4; ++j) vv[j] = S2[(tx * 4 + j) * 65 + n];
#pragma unroll
    for (int i = 0; i < 4; ++i)
#pragma unroll
      for (int j = 0; j < 4; ++j) ctx[i][j] += kv[i] * vv[j];
  }
  __syncthreads();
#pragma unroll
  for (int i = 0; i < 4; ++i)
#pragma unroll
    for (int j = 0; j < 4; ++j) S1[(ty * 4 + i) * 65 + tx * 4 + j] = ctx[i][j];
#pragma unroll
  for (int i = 0; i < 4; ++i) {
    int e = i * 1024 + t * 4;
    int d = e >> 6, n = e & 63;
    float4 qv = *(const float4*)(qt + base + e);
    S2[d * 65 + n] = qv.x; S2[d * 65 + n + 1] = qv.y; S2[d * 65 + n + 2] = qv.z; S2[d * 65 + n + 3] = qv.w;
  }
  __syncthreads();
  {
    const int d = t >> 2, qq = t & 3;
    float vals[16];
    float m = -1e30f;
#pragma unroll
    for (int k = 0; k < 16; ++k) {
      vals[k] = S2[d * 65 + qq * 16 + k];
      m = fmaxf(m, vals[k]);
    }
    m = fmaxf(m, __shfl_xor(m, 1, 64));
    m = fmaxf(m, __shfl_xor(m, 2, 64));
    float s = 0.f;
#pragma unroll
    for (int k = 0; k < 16; ++k) {
      vals[k] = __expf(vals[k] - m);
      s += vals[k];
    }
    s += __shfl_xor(s, 1, 64);
    s += __shfl_xor(s, 2, 64);
    float r = SMSCALE / s;
#pragma unroll
    for (int k = 0; k < 16; ++k) S2[d * 65 + qq * 16 + k] = vals[k] * r;
  }
  __syncthreads();
  float o[4][4] = {};
  for (int d = 0; d < 64; ++d) {
    float cv[4], qv[4];
#pragma unroll
    for (int i = 0; i < 4; ++i) cv[i] = S1[d * 65 + ty * 4 + i];
#pragma unroll
    for (int j = 0; j < 4; ++j) qv[j] = S2[d * 65 + tx * 4 + j];
#pragma unroll
    for (int i = 0; i < 4; ++i)
#pragma unroll
      for (int j = 0; j < 4; ++j) o[i][j] += cv[i] * qv[j];
  }
#pragma unroll
  for (int i = 0; i < 4; ++i) {
    float4 v;
    v.x = o[i][0]; v.y = o[i][1]; v.z = o[i][2]; v.w = o[i][3];
    *(float4*)(at + base + (ty * 4 + i) * 64 + tx * 4) = v;
  }
}

// ---------------- K4: y = attn @ w_out + b_out via MFMA (XOR-swizzled LDS transpose of at) ----------------
__global__ __launch_bounds__(256) void k_gemm_out(const float* __restrict__ at,
                                                  const short* __restrict__ wot,
                                                  const float* __restrict__ bias,
                                                  float* __restrict__ y,
                                                  float* __restrict__ sums) {
  __shared__ short As[64 * 128];  // [m=r][k=ch], 16B-unit XOR swizzle: u_phys = u ^ (m&15)
  __shared__ float red[8];
  const int t = threadIdx.x;
  const int lane = t & 63;
  const int w = t >> 6;
  const int l15 = lane & 15;
  const int q = lane >> 4;
  const int rowBase = blockIdx.x * 64;
  const int b = rowBase >> 12;
  const int r0 = rowBase & 4095;
  const size_t abase = (((size_t)(b * 128)) << 12) + r0;
  // stage at[ch][r] -> As[r][ch] bf16 via 4x4 in-register transpose
  {
    const int tr = t & 15;   // r-tile: rows tr*4..tr*4+3
    const int tk = t >> 4;   // 0..15
#pragma unroll
    for (int i = 0; i < 2; ++i) {
      const int kq = tk + 16 * i;  // 0..31 -> k = kq*4 + kc
      float4 f[4];
#pragma unroll
      for (int kc = 0; kc < 4; ++kc)
        f[kc] = *(const float4*)(at + abase + (((size_t)(kq * 4 + kc)) << 12) + tr * 4);
      const int ul = kq >> 1, h = kq & 1;
#pragma unroll
      for (int j = 0; j < 4; ++j) {
        int m = tr * 4 + j;
        s16x4 sv;
        sv[0] = f2bf(f[0][j]); sv[1] = f2bf(f[1][j]); sv[2] = f2bf(f[2][j]); sv[3] = f2bf(f[3][j]);
        *(s16x4*)(As + m * 128 + ((ul ^ (m & 15)) << 3) + h * 4) = sv;
      }
    }
  }
  __syncthreads();
  f32x4 acc[4][4] = {};
  for (int ks = 0; ks < 4; ++ks) {
    bf16x8 afr[4];
#pragma unroll
    for (int mi = 0; mi < 4; ++mi) {
      int m = mi * 16 + l15;
      int ul = ks * 4 + q;
      afr[mi] = *(const bf16x8*)(As + m * 128 + ((ul ^ (m & 15)) << 3));
    }
#pragma unroll
    for (int nj = 0; nj < 4; ++nj) {
      int c = w * 64 + nj * 16 + l15;
      bf16x8 bfr = *(const bf16x8*)(wot + (size_t)c * 128 + ks * 32 + q * 8);
#pragma unroll
      for (int mi = 0; mi < 4; ++mi)
        acc[mi][nj] = __builtin_amdgcn_mfma_f32_16x16x32_bf16(afr[mi], bfr, acc[mi][nj], 0, 0, 0);
    }
  }
  // epilogue: bias, store, fused GN partial sums
  float ls = 0.f, lss = 0.f;
#pragma unroll
  for (int mi = 0; mi < 4; ++mi) {
    int r = rowBase + mi * 16 + q * 4;
#pragma unroll
    for (int nj = 0; nj < 4; ++nj) {
      int c = w * 64 + nj * 16 + l15;
      float bv = bias[c];
#pragma unroll
      for (int rg = 0; rg < 4; ++rg) {
        float v = acc[mi][nj][rg] + bv;
        y[(size_t)(r + rg) * NC + c] = v;
        ls += v;
        lss += v * v;
      }
    }
  }
#pragma unroll
  for (int off = 32; off; off >>= 1) {
    ls += __shfl_xor(ls, off, 64);
    lss += __shfl_xor(lss, off, 64);
  }
  if (lane == 0) {
    red[w] = ls;
    red[4 + w] = lss;
  }
  __syncthreads();
  if (t == 0) {
    float S = red[0] + red[1] + red[2] + red[3];
    float SS = red[4] + red[5] + red[6] + red[7];
    atomicAdd(&sums[2 * b], S);
    atomicAdd(&sums[2 * b + 1], SS);
  }
}

// ---------------- K5: GroupNorm(1 group) finalize, in place ----------------
__global__ __launch_bounds__(256) void k_gnorm(float* __restrict__ y,
                                               const float* __restrict__ sums,
                                               const float* __restrict__ gs,
                                               const float* __restrict__ gb) {
  size_t i0 = ((size_t)blockIdx.x * 256 + threadIdx.x) * 4;
  int b = (int)(i0 >> 20);
  int c = (int)(i0 & 255);
  const float invN = 1.0f / 1048576.0f;
  float mean = sums[2 * b] * invN;
  float var = sums[2 * b + 1] * invN - mean * mean;
  float inv = rsqrtf(var + 1e-6f);
  float4 v = *((const float4*)(y + i0));
  float4 g = *((const float4*)(gs + c));
  float4 bb = *((const float4*)(gb + c));
  float4 r;
  r.x = (v.x - mean) * inv * g.x + bb.x;
  r.y = (v.y - mean) * inv * g.y + bb.y;
  r.z = (v.z - mean) * inv * g.z + bb.z;
  r.w = (v.w - mean) * inv * g.w + bb.w;
  *((float4*)(y + i0)) = r;
}

extern "C" void kernel_launch(void* const* d_in, const int* in_sizes, int n_in,
                              void* d_out, int out_size, void* d_ws, size_t ws_size,
                              hipStream_t stream) {
  const float* x = (const float*)d_in[0];
  const float* w_qkv = (const float*)d_in[1];
  const float* w_out = (const float*)d_in[2];
  const float* b_out = (const float*)d_in[3];
  const float* gn_scale = (const float*)d_in[4];
  const float* gn_bias = (const float*)d_in[5];
  float* out = (float*)d_out;

  char* ws = (char*)d_ws;
  const size_t SLAB = (size_t)67108864;  // 64 MiB
  float* qt = (float*)ws;
  float* kt = (float*)(ws + SLAB);
  float* vt = (float*)(ws + 2 * SLAB);
  float* at = qt;  // alias: k_attn consumes its qt slice before writing its at slice
  float* sums = (float*)(ws + 3 * SLAB);
  short* wqt = (short*)(ws + 3 * SLAB + 1024);
  short* wot = (short*)(ws + 3 * SLAB + 1024 + 196608);

  hipMemsetAsync(sums, 0, 64 * sizeof(float), stream);

  k_prep_w<<<384, 256, 0, stream>>>(w_qkv, w_out, wqt, wot);
  k_gemm_qkv<<<2048, 256, 0, stream>>>(x, wqt, qt, kt, vt);
  k_softmax_k<<<2048, 256, 0, stream>>>(kt);
  k_attn<<<dim3(128, 32), 256, 0, stream>>>(kt, vt, qt, at);
  k_gemm_out<<<2048, 256, 0, stream>>>(at, wot, b_out, out, sums);
  k_gnorm<<<32768, 256, 0, stream>>>(out, sums, gn_scale, gn_bias);
}